// Round 2
// baseline (197.058 us; speedup 1.0000x reference)
//
#include <hip/hip_runtime.h>
#include <hip/hip_bf16.h>
#include <stdint.h>
#include <stddef.h>

// ---------- types ----------
typedef __bf16 b16;
typedef __bf16 b16x4 __attribute__((ext_vector_type(4)));
typedef __bf16 b16x8 __attribute__((ext_vector_type(8)));
typedef float  f32x4 __attribute__((ext_vector_type(4)));

#define LOG2E 1.4426950408889634f
#define QSCALE (0.125f * LOG2E)   // 1/sqrt(64) folded with log2(e): softmax in exp2 domain

#if __has_builtin(__builtin_amdgcn_exp2f)
#define EXP2F(x) __builtin_amdgcn_exp2f(x)
#else
#define EXP2F(x) exp2f(x)
#endif

typedef __attribute__((address_space(1))) void gvoid;
typedef __attribute__((address_space(3))) void svoid;

// async global->LDS, 16B per lane. LDS dest must be wave-uniform base + lane*16.
__device__ __forceinline__ void async_cp16(void* lds, const void* g) {
    __builtin_amdgcn_global_load_lds((gvoid*)(void*)g, (svoid*)lds, 16, 0, 0);
}

// XOR swizzle on 16B chunk index: spreads row bits {0,1,2} and bit3 over the
// 8 chunk slots so every ds_read_b128 pattern used below hits each slot with
// exactly 8 of 64 lanes (the 1024B/128B minimum -> conflict-free).
#define SW(r) ((((r) & 7)) ^ (((r) >> 1) & 4))

// ---------- kernel 1: x fp32 -> bf16 ----------
__global__ __launch_bounds__(256) void k_cvt_x(const float* __restrict__ x,
                                               b16* __restrict__ xb) {
    int i = (blockIdx.x * 256 + threadIdx.x) * 4;
    float4 v = *(const float4*)(x + i);
    b16x4 o = { (b16)v.x, (b16)v.y, (b16)v.z, (b16)v.w };
    *(b16x4*)(xb + i) = o;
}

// ---------- kernel 2: W[k][n] fp32 -> Wt[n][k] bf16 (per 32x32 tile) ----------
__global__ __launch_bounds__(256) void k_transpose(const float* __restrict__ Wq,
                                                   const float* __restrict__ Wk,
                                                   const float* __restrict__ Wv,
                                                   const float* __restrict__ Wo,
                                                   b16* __restrict__ WtQKV,
                                                   b16* __restrict__ Wot) {
    __shared__ float t[32][33];
    const int z = blockIdx.z;
    const float* W = (z == 0) ? Wq : (z == 1) ? Wk : (z == 2) ? Wv : Wo;
    const int k0 = blockIdx.x * 32, n0 = blockIdx.y * 32;
    const int tr = threadIdx.x >> 3, tc4 = (threadIdx.x & 7) * 4;
    float4 v = *(const float4*)(W + (size_t)(k0 + tr) * 1024 + n0 + tc4);
    t[tr][tc4 + 0] = v.x; t[tr][tc4 + 1] = v.y;
    t[tr][tc4 + 2] = v.z; t[tr][tc4 + 3] = v.w;
    __syncthreads();
    b16* dst = (z < 3) ? (WtQKV + ((size_t)z << 20)) : Wot;
    b16x4 o = { (b16)t[tc4 + 0][tr], (b16)t[tc4 + 1][tr],
                (b16)t[tc4 + 2][tr], (b16)t[tc4 + 3][tr] };
    *(b16x4*)(dst + (size_t)(n0 + tr) * 1024 + k0 + tc4) = o;
}

// ---------- shared GEMM core: C[128x128] = A[128xK] * Bt[128xK]^T, K=1024 ----------
__device__ __forceinline__ void gemm128_core(const b16* __restrict__ Ab,
                                             const b16* __restrict__ Bb,
                                             b16* As, b16* Bs, int tid,
                                             f32x4 acc[4][4]) {
    const int lane = tid & 63, wave = tid >> 6;
    const int wm = wave & 1, wn = wave >> 1;
    const int quad = lane >> 4, lc = lane & 15;
    const int ci0 = tid, ci1 = tid + 256;
    for (int k0 = 0; k0 < 1024; k0 += 32) {
        __syncthreads();
        async_cp16(As + ci0 * 8, Ab + (ci0 >> 2) * 1024 + k0 + (ci0 & 3) * 8);
        async_cp16(As + ci1 * 8, Ab + (ci1 >> 2) * 1024 + k0 + (ci1 & 3) * 8);
        async_cp16(Bs + ci0 * 8, Bb + (ci0 >> 2) * 1024 + k0 + (ci0 & 3) * 8);
        async_cp16(Bs + ci1 * 8, Bb + (ci1 >> 2) * 1024 + k0 + (ci1 & 3) * 8);
        __syncthreads();
        b16x8 af[4], bfr[4];
#pragma unroll
        for (int mt = 0; mt < 4; ++mt)
            af[mt] = *(const b16x8*)(As + (wm * 64 + mt * 16 + lc) * 32 + quad * 8);
#pragma unroll
        for (int nt = 0; nt < 4; ++nt)
            bfr[nt] = *(const b16x8*)(Bs + (wn * 64 + nt * 16 + lc) * 32 + quad * 8);
#pragma unroll
        for (int mt = 0; mt < 4; ++mt)
#pragma unroll
            for (int nt = 0; nt < 4; ++nt)
                acc[mt][nt] = __builtin_amdgcn_mfma_f32_16x16x32_bf16(
                    af[mt], bfr[nt], acc[mt][nt], 0, 0, 0);
    }
}

// ---------- kernel 3: fused QKV projection ----------
__global__ __launch_bounds__(256, 2) void k_gemm_qkv(
    const b16* __restrict__ A, const b16* __restrict__ Bt,
    const float* __restrict__ bq, const float* __restrict__ bk,
    const float* __restrict__ bv,
    b16* __restrict__ Qg, b16* __restrict__ Kg, b16* __restrict__ Vtg) {
    __shared__ __align__(16) b16 As[128 * 32];
    __shared__ __align__(16) b16 Bs[128 * 32];
    const int bm = blockIdx.x, bn = blockIdx.y;
    const int tid = threadIdx.x;
    const int lane = tid & 63, wave = tid >> 6;
    const int wm = wave & 1, wn = wave >> 1;
    const int quad = lane >> 4, lc = lane & 15;

    f32x4 acc[4][4] = {};
    gemm128_core(A + (size_t)(bm * 128) * 1024, Bt + (size_t)(bn * 128) * 1024,
                 As, Bs, tid, acc);

    const int mat = bn >> 3;
    const float* bp = (mat == 0) ? bq : (mat == 1) ? bk : bv;
#pragma unroll
    for (int nt = 0; nt < 4; ++nt) {
        const int n = bn * 128 + wn * 64 + nt * 16 + lc;
        const int cm = n & 1023;
        const int h = cm >> 6, dh = cm & 63;
        const float bval = bp[cm];
#pragma unroll
        for (int mt = 0; mt < 4; ++mt) {
            const int m0 = bm * 128 + wm * 64 + mt * 16 + quad * 4;
            const int b = m0 >> 11;
            const int bh = b * 16 + h;
            const int s0 = m0 & 2047;
            if (mat == 2) {
                b16x4 o;
#pragma unroll
                for (int r = 0; r < 4; ++r) o[r] = (b16)(acc[mt][nt][r] + bval);
                *(b16x4*)(Vtg + (size_t)(bh * 64 + dh) * 2048 + s0) = o;
            } else if (mat == 0) {
#pragma unroll
                for (int r = 0; r < 4; ++r)
                    Qg[(size_t)(bh * 2048 + s0 + r) * 64 + dh] =
                        (b16)((acc[mt][nt][r] + bval) * QSCALE);
            } else {
#pragma unroll
                for (int r = 0; r < 4; ++r)
                    Kg[(size_t)(bh * 2048 + s0 + r) * 64 + dh] =
                        (b16)(acc[mt][nt][r] + bval);
            }
        }
    }
}

// ---------- flash staging: one 64x64 K tile + one 64x64 V^T tile -> LDS ----------
// 4 async_cp16 per thread (2 K + 2 V). SW() 16B-chunk swizzle on the global
// source so LDS stays linear for global_load_lds (guide §5 caveat / m173).
__device__ __forceinline__ void flash_stage(b16* Kd, b16* Vd,
                                            const b16* __restrict__ Kbh,
                                            const b16* __restrict__ Vbh,
                                            int kt, int tid) {
#pragma unroll
    for (int i = 0; i < 2; ++i) {
        const int ci = tid + i * 256;          // 0..511
        const int r = ci >> 3, cs = ci & 7;
        const int gc = cs ^ SW(r);             // XOR chunk swizzle
        async_cp16(Kd + ci * 8, Kbh + (size_t)(kt * 64 + r) * 64 + gc * 8);
        async_cp16(Vd + ci * 8, Vbh + (size_t)r * 2048 + kt * 64 + gc * 8);
    }
}

// ---------- kernel 4: flash attention, no-max exp2 softmax ----------
// Block: 128 q rows of one (b,h), 4 waves x 32 q. Key tiles of 64, split over
// `part` (additive partials; merge divides by l at the end).
// In-register P: the QK^T A-operand loads K rows PERMUTED
// (row = ks*32 + (lc>>2)*8 + t*4 + (lc&3)) so the S^T output leaves each lane
// holding exactly keys quad*8+{t*4+r} -> after exp2+cast the PV A-fragment is
// assembled with ZERO cross-lane ops and P never touches LDS.
// LDS = 32KB K/V double-buffer -> 4 blocks/CU (launch_bounds caps VGPR at 128).
__global__ __launch_bounds__(256, 4) void k_flash(
    const b16* __restrict__ Qg, const b16* __restrict__ Kg,
    const b16* __restrict__ Vtg,
    float* __restrict__ Opart, float* __restrict__ lpart,
    b16* __restrict__ AO, int ktiles, int direct, int np) {
    __shared__ __align__(16) b16 Ks[2 * 64 * 64];   // double-buffered K tile
    __shared__ __align__(16) b16 Vs[2 * 64 * 64];   // double-buffered V^T tile
    __shared__ float Lred[4][32];                   // direct-path l exchange

    // XCD swizzle: bid = qb*(32*np) + bh*np + part. Same-(bh,part) blocks differ
    // by a multiple of 32*np (=0 mod 8) -> same XCD under round-robin dispatch.
    const int bid = blockIdx.x;
    const int gstride = np << 5;
    const int qb = bid / gstride;
    const int rem = bid - qb * gstride;
    const int bh = rem / np;
    const int part = rem - bh * np;

    const int tid = threadIdx.x, lane = tid & 63, wave = tid >> 6;
    const int quad = lane >> 4, lc = lane & 15;

    const b16* Kbh = Kg + (size_t)bh * 2048 * 64;
    const b16* Vbh = Vtg + (size_t)bh * 64 * 2048;
    const int kt0 = part * ktiles, ktE = kt0 + ktiles;

    // prologue: stage first tile into buffer 0 (latency hides under Q loads)
    flash_stage(Ks, Vs, Kbh, Vbh, kt0, tid);

    // Q fragments (B-operand: n=q=lc, k=d=quad*8+j), 32 q rows per wave
    const b16* Qbase = Qg + ((size_t)bh * 2048 + qb * 128 + wave * 32) * 64;
    b16x8 qf[2][2];
#pragma unroll
    for (int qt = 0; qt < 2; ++qt)
#pragma unroll
        for (int ch = 0; ch < 2; ++ch)
            qf[qt][ch] = *(const b16x8*)(Qbase + (qt * 16 + lc) * 64 + ch * 32 + quad * 8);

    f32x4 oacc[2][4] = {};
    float lsum[2] = {0.f, 0.f};

    for (int kt = kt0; kt < ktE; ++kt) {
        const int cur = (kt - kt0) & 1;
        const b16* Kc = Ks + cur * 4096;
        const b16* Vc = Vs + cur * 4096;

        if (kt + 1 < ktE) {
            // issue next tile's 4 loads, then wait only for current tile's 4
            flash_stage(Ks + (cur ^ 1) * 4096, Vs + (cur ^ 1) * 4096,
                        Kbh, Vbh, kt + 1, tid);
            asm volatile("s_waitcnt vmcnt(4)" ::: "memory");
        } else {
            asm volatile("s_waitcnt vmcnt(0)" ::: "memory");
        }
        __builtin_amdgcn_s_barrier();          // all waves' cur-tile loads done
        __builtin_amdgcn_sched_barrier(0);     // pin: no ds_read hoists above

#pragma unroll
        for (int ks = 0; ks < 2; ++ks) {
            // QK^T with permuted key rows; P stays in registers
            b16x8 pf[2];
#pragma unroll
            for (int t = 0; t < 2; ++t) {
                // A-operand: lane reads K row = perm(lc), d-chunk = ch*4+quad
                const int krow = ks * 32 + (lc >> 2) * 8 + t * 4 + (lc & 3);
                b16x8 kf[2];
#pragma unroll
                for (int ch = 0; ch < 2; ++ch) {
                    const int slot = (ch * 4 + quad) ^ SW(krow);
                    kf[ch] = *(const b16x8*)(Kc + krow * 64 + slot * 8);
                }
#pragma unroll
                for (int qt = 0; qt < 2; ++qt) {
                    f32x4 s = {};
                    __builtin_amdgcn_s_setprio(1);
                    s = __builtin_amdgcn_mfma_f32_16x16x32_bf16(kf[0], qf[qt][0], s, 0, 0, 0);
                    s = __builtin_amdgcn_mfma_f32_16x16x32_bf16(kf[1], qf[qt][1], s, 0, 0, 0);
                    __builtin_amdgcn_s_setprio(0);
                    // lane now holds S[key = ks*32 + quad*8 + t*4 + r][q=qt*16+lc]
                    float e0 = EXP2F(s[0]), e1 = EXP2F(s[1]);
                    float e2 = EXP2F(s[2]), e3 = EXP2F(s[3]);
                    lsum[qt] += (e0 + e1) + (e2 + e3);
                    pf[qt][t * 4 + 0] = (b16)e0;
                    pf[qt][t * 4 + 1] = (b16)e1;
                    pf[qt][t * 4 + 2] = (b16)e2;
                    pf[qt][t * 4 + 3] = (b16)e3;
                }
            }
            // O += P V  (A=pf: q=lc, key=quad*8+j; B=V^T: d=lc, key=quad*8+j)
            b16x8 vf[4];
#pragma unroll
            for (int dt = 0; dt < 4; ++dt) {
                const int row = dt * 16 + lc;
                const int slot = (ks * 4 + quad) ^ SW(row);
                vf[dt] = *(const b16x8*)(Vc + row * 64 + slot * 8);
            }
            __builtin_amdgcn_s_setprio(1);
#pragma unroll
            for (int qt = 0; qt < 2; ++qt)
#pragma unroll
                for (int dt = 0; dt < 4; ++dt)
                    oacc[qt][dt] = __builtin_amdgcn_mfma_f32_16x16x32_bf16(
                        pf[qt], vf[dt], oacc[qt][dt], 0, 0, 0);
            __builtin_amdgcn_s_setprio(0);
        }

        __builtin_amdgcn_sched_barrier(0);     // pin: no ds_read sinks below
        __builtin_amdgcn_s_barrier();          // all waves done reading cur
    }

    // reduce l across quads (lane holds l for q=qt*16+lc, partial over keys)
#pragma unroll
    for (int qt = 0; qt < 2; ++qt) {
        lsum[qt] += __shfl_xor(lsum[qt], 16, 64);
        lsum[qt] += __shfl_xor(lsum[qt], 32, 64);
    }

    if (!direct) {
        float* Op = Opart + ((size_t)(part * 32 + bh) * 2048 + qb * 128 + wave * 32) * 64;
#pragma unroll
        for (int qt = 0; qt < 2; ++qt)
#pragma unroll
            for (int dt = 0; dt < 4; ++dt)
#pragma unroll
                for (int r = 0; r < 4; ++r)
                    Op[(qt * 16 + quad * 4 + r) * 64 + dt * 16 + lc] = oacc[qt][dt][r];
        if (quad == 0) {
            float* lp = lpart + (size_t)(part * 32 + bh) * 2048 + qb * 128 + wave * 32;
#pragma unroll
            for (int qt = 0; qt < 2; ++qt) lp[qt * 16 + lc] = lsum[qt];
        }
    } else {
        // single-part fallback: redistribute l via per-wave LDS, write AO directly
        if (quad == 0) {
#pragma unroll
            for (int qt = 0; qt < 2; ++qt) Lred[wave][qt * 16 + lc] = lsum[qt];
        }
        const int b = bh >> 4, h = bh & 15;
#pragma unroll
        for (int qt = 0; qt < 2; ++qt)
#pragma unroll
            for (int r = 0; r < 4; ++r) {
                const float inv = 1.0f / Lred[wave][qt * 16 + quad * 4 + r];
                const int s = qb * 128 + wave * 32 + qt * 16 + quad * 4 + r;
#pragma unroll
                for (int dt = 0; dt < 4; ++dt)
                    AO[(size_t)(b * 2048 + s) * 1024 + h * 64 + dt * 16 + lc] =
                        (b16)(oacc[qt][dt][r] * inv);
            }
    }
}

// ---------- kernel 4b: merge partials: AO = (O0+O1)/(l0+l1) ----------
__global__ __launch_bounds__(256) void k_merge(const float* __restrict__ Opart,
                                               const float* __restrict__ lpart,
                                               b16* __restrict__ AO, int np) {
    const int bh = blockIdx.y;
    const int q = blockIdx.x * 16 + (threadIdx.x >> 4);
    const int d4 = (threadIdx.x & 15) * 4;
    const size_t qi = (size_t)bh * 2048 + q;
    f32x4 o = *(const f32x4*)(Opart + qi * 64 + d4);
    float l = lpart[qi];
    if (np == 2) {
        o += *(const f32x4*)(Opart + (qi + (size_t)32 * 2048) * 64 + d4);
        l += lpart[qi + (size_t)32 * 2048];
    }
    const float inv = 1.0f / l;
    const int b = bh >> 4, h = bh & 15;
    b16x4 ob = { (b16)(o[0] * inv), (b16)(o[1] * inv),
                 (b16)(o[2] * inv), (b16)(o[3] * inv) };
    *(b16x4*)(AO + (size_t)(b * 2048 + q) * 1024 + h * 64 + d4) = ob;
}

// ---------- kernel 5: output projection, fp32 epilogue ----------
__global__ __launch_bounds__(256, 2) void k_gemm_out(
    const b16* __restrict__ A, const b16* __restrict__ Bt,
    const float* __restrict__ bo, float* __restrict__ out) {
    __shared__ __align__(16) b16 As[128 * 32];
    __shared__ __align__(16) b16 Bs[128 * 32];
    const int bm = blockIdx.x, bn = blockIdx.y;
    const int tid = threadIdx.x;
    const int lane = tid & 63, wave = tid >> 6;
    const int wm = wave & 1, wn = wave >> 1;
    const int quad = lane >> 4, lc = lane & 15;

    f32x4 acc[4][4] = {};
    gemm128_core(A + (size_t)(bm * 128) * 1024, Bt + (size_t)(bn * 128) * 1024,
                 As, Bs, tid, acc);

#pragma unroll
    for (int nt = 0; nt < 4; ++nt) {
        const int n = bn * 128 + wn * 64 + nt * 16 + lc;
        const float bval = bo[n];
#pragma unroll
        for (int mt = 0; mt < 4; ++mt) {
            const int m0 = bm * 128 + wm * 64 + mt * 16 + quad * 4;
#pragma unroll
            for (int r = 0; r < 4; ++r)
                out[(size_t)(m0 + r) * 1024 + n] = acc[mt][nt][r] + bval;
        }
    }
}

// ---------- launcher ----------
extern "C" void kernel_launch(void* const* d_in, const int* in_sizes, int n_in,
                              void* d_out, int out_size, void* d_ws, size_t ws_size,
                              hipStream_t stream) {
    const float* x  = (const float*)d_in[0];
    const float* Wq = (const float*)d_in[1];
    const float* bq = (const float*)d_in[2];
    const float* Wk = (const float*)d_in[3];
    const float* bk = (const float*)d_in[4];
    const float* Wv = (const float*)d_in[5];
    const float* bv = (const float*)d_in[6];
    const float* Wo = (const float*)d_in[7];
    const float* bo = (const float*)d_in[8];
    float* out = (float*)d_out;

    char* ws = (char*)d_ws;
    const size_t MB = 1024 * 1024;
    b16* Xb  = (b16*)(ws);             // [4096][1024] bf16 (dead after qkv)
    b16* AO  = (b16*)(ws);             // [4096][1024] bf16 (overlay on Xb)
    b16* WtQ = (b16*)(ws + 8 * MB);    // [3072][1024] bf16
    b16* Wot = (b16*)(ws + 14 * MB);   // [1024][1024] bf16
    b16* Qg  = (b16*)(ws + 16 * MB);   // [32][2048][64] bf16 (pre-scaled)
    b16* Kg  = (b16*)(ws + 24 * MB);   // [32][2048][64] bf16
    b16* Vtg = (b16*)(ws + 32 * MB);   // [32][64][2048] bf16

    // attention partials (np=2 key-split if workspace allows)
    const size_t need2 = 40 * MB + 2 * (16 * MB) + 2 * 256 * 1024;
    const int np = (ws_size >= need2) ? 2 : 1;
    float* Opart = (float*)(ws + 40 * MB);                       // [np][32][2048][64] f32
    float* lpart = (float*)(ws + 40 * MB + (size_t)np * 16 * MB); // [np][32][2048] f32
    const int direct = (np == 1);

    k_cvt_x<<<4096, 256, 0, stream>>>(x, Xb);
    k_transpose<<<dim3(32, 32, 4), 256, 0, stream>>>(Wq, Wk, Wv, Wo, WtQ, Wot);
    k_gemm_qkv<<<dim3(32, 24), 256, 0, stream>>>(Xb, WtQ, bq, bk, bv, Qg, Kg, Vtg);
    k_flash<<<dim3(16 * 32 * np), 256, 0, stream>>>(Qg, Kg, Vtg, Opart, lpart, AO,
                                                    32 / np, direct, np);
    if (!direct)
        k_merge<<<dim3(128, 32), 256, 0, stream>>>(Opart, lpart, AO, np);
    k_gemm_out<<<dim3(32, 8), 256, 0, stream>>>(AO, Wot, bo, out);
}

// Round 4
// 188.727 us; speedup vs baseline: 1.0441x; 1.0441x over previous
//
#include <hip/hip_runtime.h>
#include <hip/hip_bf16.h>
#include <stdint.h>
#include <stddef.h>

// ---------- types ----------
typedef __bf16 b16;
typedef __bf16 b16x4 __attribute__((ext_vector_type(4)));
typedef __bf16 b16x8 __attribute__((ext_vector_type(8)));
typedef float  f32x4 __attribute__((ext_vector_type(4)));

#define LOG2E 1.4426950408889634f
#define QSCALE (0.125f * LOG2E)   // 1/sqrt(64) folded with log2(e): softmax in exp2 domain

#if __has_builtin(__builtin_amdgcn_exp2f)
#define EXP2F(x) __builtin_amdgcn_exp2f(x)
#else
#define EXP2F(x) exp2f(x)
#endif

typedef __attribute__((address_space(1))) void gvoid;
typedef __attribute__((address_space(3))) void svoid;

// async global->LDS, 16B per lane. LDS dest must be wave-uniform base + lane*16.
__device__ __forceinline__ void async_cp16(void* lds, const void* g) {
    __builtin_amdgcn_global_load_lds((gvoid*)(void*)g, (svoid*)lds, 16, 0, 0);
}

// XOR swizzle on 16B chunk index (bank-group spread for the permuted-row reads)
#define SW(r) ((((r) & 7)) ^ (((r) >> 1) & 4))

// ---------- kernel 1: prep = x fp32->bf16 (z==4) + W transposes (z<4) ----------
__global__ __launch_bounds__(256) void k_prep(const float* __restrict__ x,
                                              const float* __restrict__ Wq,
                                              const float* __restrict__ Wk,
                                              const float* __restrict__ Wv,
                                              const float* __restrict__ Wo,
                                              b16* __restrict__ Xb,
                                              b16* __restrict__ WtQKV,
                                              b16* __restrict__ Wot) {
    const int z = blockIdx.z;
    if (z == 4) {
        // convert x: 1024 blocks * 4096 floats = 2*2048*1024 exactly
        const int blk = blockIdx.y * 32 + blockIdx.x;
        const float* src = x + (size_t)blk * 4096;
        b16* dst = Xb + (size_t)blk * 4096;
#pragma unroll
        for (int c = 0; c < 4; ++c) {
            const int i = c * 1024 + threadIdx.x * 4;
            float4 v = *(const float4*)(src + i);
            b16x4 o = { (b16)v.x, (b16)v.y, (b16)v.z, (b16)v.w };
            *(b16x4*)(dst + i) = o;
        }
        return;
    }
    __shared__ float t[32][33];
    const float* W = (z == 0) ? Wq : (z == 1) ? Wk : (z == 2) ? Wv : Wo;
    const int k0 = blockIdx.x * 32, n0 = blockIdx.y * 32;
    const int tr = threadIdx.x >> 3, tc4 = (threadIdx.x & 7) * 4;
    float4 v = *(const float4*)(W + (size_t)(k0 + tr) * 1024 + n0 + tc4);
    t[tr][tc4 + 0] = v.x; t[tr][tc4 + 1] = v.y;
    t[tr][tc4 + 2] = v.z; t[tr][tc4 + 3] = v.w;
    __syncthreads();
    b16* dst = (z < 3) ? (WtQKV + ((size_t)z << 20)) : Wot;
    b16x4 o = { (b16)t[tc4 + 0][tr], (b16)t[tc4 + 1][tr],
                (b16)t[tc4 + 2][tr], (b16)t[tc4 + 3][tr] };
    *(b16x4*)(dst + (size_t)(n0 + tr) * 1024 + k0 + tc4) = o;
}

// ---------- shared GEMM core: C[128x128] = A[128xK] * Bt[128xK]^T, K=1024 ----------
// 2-phase double-buffered staging with counted vmcnt: next K-step's
// global_load_lds stay in flight across the barrier (never vmcnt(0) mid-loop).
__device__ __forceinline__ void gemm128_core(const b16* __restrict__ Ag,
                                             const b16* __restrict__ Bg,
                                             b16* As, b16* Bs, int tid,
                                             f32x4 acc[4][4]) {
    const int lane = tid & 63, wave = tid >> 6;
    const int wm = wave & 1, wn = wave >> 1;
    const int quad = lane >> 4, lc = lane & 15;
    const int ci0 = tid, ci1 = tid + 256;
    const b16* a0 = Ag + (ci0 >> 2) * 1024 + (ci0 & 3) * 8;
    const b16* a1 = Ag + (ci1 >> 2) * 1024 + (ci1 & 3) * 8;
    const b16* b0 = Bg + (ci0 >> 2) * 1024 + (ci0 & 3) * 8;
    const b16* b1 = Bg + (ci1 >> 2) * 1024 + (ci1 & 3) * 8;

#define GSTAGE(BUF, K0) do {                                   \
        async_cp16(As + (BUF) * 4096 + ci0 * 8, a0 + (K0));    \
        async_cp16(As + (BUF) * 4096 + ci1 * 8, a1 + (K0));    \
        async_cp16(Bs + (BUF) * 4096 + ci0 * 8, b0 + (K0));    \
        async_cp16(Bs + (BUF) * 4096 + ci1 * 8, b1 + (K0));    \
    } while (0)

    auto gcompute = [&](int buf) {
        const b16* Al = As + buf * 4096;
        const b16* Bl = Bs + buf * 4096;
        b16x8 af[4], bfr[4];
#pragma unroll
        for (int mt = 0; mt < 4; ++mt)
            af[mt] = *(const b16x8*)(Al + (wm * 64 + mt * 16 + lc) * 32 + quad * 8);
#pragma unroll
        for (int nt = 0; nt < 4; ++nt)
            bfr[nt] = *(const b16x8*)(Bl + (wn * 64 + nt * 16 + lc) * 32 + quad * 8);
#pragma unroll
        for (int mt = 0; mt < 4; ++mt)
#pragma unroll
            for (int nt = 0; nt < 4; ++nt)
                acc[mt][nt] = __builtin_amdgcn_mfma_f32_16x16x32_bf16(
                    af[mt], bfr[nt], acc[mt][nt], 0, 0, 0);
    };

    GSTAGE(0, 0);
    for (int k0 = 0; k0 < 1024; k0 += 64) {
        // half 0: compute buf0 (K-step k0), stage buf1 (K-step k0+32)
        GSTAGE(1, k0 + 32);
        asm volatile("s_waitcnt vmcnt(4)" ::: "memory");
        __builtin_amdgcn_s_barrier();
        __builtin_amdgcn_sched_barrier(0);
        gcompute(0);
        __builtin_amdgcn_sched_barrier(0);
        __builtin_amdgcn_s_barrier();
        // half 1: compute buf1 (K-step k0+32), stage buf0 (K-step k0+64)
        if (k0 + 64 < 1024) {
            GSTAGE(0, k0 + 64);
            asm volatile("s_waitcnt vmcnt(4)" ::: "memory");
        } else {
            asm volatile("s_waitcnt vmcnt(0)" ::: "memory");
        }
        __builtin_amdgcn_s_barrier();
        __builtin_amdgcn_sched_barrier(0);
        gcompute(1);
        __builtin_amdgcn_sched_barrier(0);
        __builtin_amdgcn_s_barrier();
    }
#undef GSTAGE
}

// ---------- kernel 2: fused QKV projection ----------
__global__ __launch_bounds__(256, 2) void k_gemm_qkv(
    const b16* __restrict__ A, const b16* __restrict__ Bt,
    const float* __restrict__ bq, const float* __restrict__ bk,
    const float* __restrict__ bv,
    b16* __restrict__ Qg, b16* __restrict__ Kg, b16* __restrict__ Vtg) {
    __shared__ __align__(16) b16 As[2 * 128 * 32];
    __shared__ __align__(16) b16 Bs[2 * 128 * 32];
    const int bm = blockIdx.x, bn = blockIdx.y;
    const int tid = threadIdx.x;
    const int lane = tid & 63, wave = tid >> 6;
    const int wm = wave & 1, wn = wave >> 1;
    const int quad = lane >> 4, lc = lane & 15;

    f32x4 acc[4][4] = {};
    gemm128_core(A + (size_t)(bm * 128) * 1024, Bt + (size_t)(bn * 128) * 1024,
                 As, Bs, tid, acc);

    const int mat = bn >> 3;
    const float* bp = (mat == 0) ? bq : (mat == 1) ? bk : bv;
#pragma unroll
    for (int nt = 0; nt < 4; ++nt) {
        const int n = bn * 128 + wn * 64 + nt * 16 + lc;
        const int cm = n & 1023;
        const int h = cm >> 6, dh = cm & 63;
        const float bval = bp[cm];
#pragma unroll
        for (int mt = 0; mt < 4; ++mt) {
            const int m0 = bm * 128 + wm * 64 + mt * 16 + quad * 4;
            const int b = m0 >> 11;
            const int bh = b * 16 + h;
            const int s0 = m0 & 2047;
            if (mat == 2) {
                b16x4 o;
#pragma unroll
                for (int r = 0; r < 4; ++r) o[r] = (b16)(acc[mt][nt][r] + bval);
                *(b16x4*)(Vtg + (size_t)(bh * 64 + dh) * 2048 + s0) = o;
            } else if (mat == 0) {
#pragma unroll
                for (int r = 0; r < 4; ++r)
                    Qg[(size_t)(bh * 2048 + s0 + r) * 64 + dh] =
                        (b16)((acc[mt][nt][r] + bval) * QSCALE);
            } else {
#pragma unroll
                for (int r = 0; r < 4; ++r)
                    Kg[(size_t)(bh * 2048 + s0 + r) * 64 + dh] =
                        (b16)(acc[mt][nt][r] + bval);
            }
        }
    }
}

// ---------- kernel 3: flash attention, no-max exp2 softmax, np=1 direct ----------
// Block: 64 q rows of one (b,h), 4 waves x 16 q rows. All 32 key tiles scanned.
// In-register P via permuted K rows (krow = ks*32 + (lc>>2)*8 + t*4 + (lc&3)):
// S^T output leaves each lane holding exactly keys quad*8+{t*4+r} -> PV
// A-fragment assembled with zero cross-lane ops; P never touches LDS.
// Double-buffered K/V with counted vmcnt; manual unroll-2 so buffer bases are
// static and all LDS addresses hoist out of the loop.
__global__ __launch_bounds__(256, 4) void k_flash(
    const b16* __restrict__ Qg, const b16* __restrict__ Kg,
    const b16* __restrict__ Vtg, b16* __restrict__ AO) {
    __shared__ __align__(16) b16 Ks[2 * 64 * 64];   // double-buffered K tile
    __shared__ __align__(16) b16 Vs[2 * 64 * 64];   // double-buffered V^T tile
    __shared__ float Lred[4][16];                   // per-wave l exchange
    // LDS = 32.25 KiB -> 4 blocks/CU

    // bid = qb*32 + bh: same-bh blocks differ by 32 (0 mod 8) -> same XCD.
    const int bid = blockIdx.x;
    const int qb = bid >> 5;
    const int bh = bid & 31;

    const int tid = threadIdx.x, lane = tid & 63, wave = tid >> 6;
    const int quad = lane >> 4, lc = lane & 15;

    const b16* Kbh = Kg + (size_t)bh * 2048 * 64;
    const b16* Vbh = Vtg + (size_t)bh * 64 * 2048;

    // staging source pointers (advance per tile; LDS dest stays linear)
    const int ci0 = tid, ci1 = tid + 256;
    const int r0 = ci0 >> 3, gc0 = (ci0 & 7) ^ SW(r0);
    const int r1 = ci1 >> 3, gc1 = (ci1 & 7) ^ SW(r1);
    const b16* pK0 = Kbh + r0 * 64 + gc0 * 8;
    const b16* pK1 = Kbh + r1 * 64 + gc1 * 8;
    const b16* pV0 = Vbh + (size_t)r0 * 2048 + gc0 * 8;
    const b16* pV1 = Vbh + (size_t)r1 * 2048 + gc1 * 8;

#define FSTAGE(BUF) do {                                   \
        async_cp16(Ks + (BUF) * 4096 + ci0 * 8, pK0);      \
        async_cp16(Ks + (BUF) * 4096 + ci1 * 8, pK1);      \
        async_cp16(Vs + (BUF) * 4096 + ci0 * 8, pV0);      \
        async_cp16(Vs + (BUF) * 4096 + ci1 * 8, pV1);      \
        pK0 += 4096; pK1 += 4096; pV0 += 64; pV1 += 64;    \
    } while (0)

    // prologue: stage tile 0 (latency hides under Q loads)
    FSTAGE(0);

    // Q fragments (B-operand: n=q=lc, k=d=quad*8+j), 16 q rows per wave
    const b16* Qbase = Qg + ((size_t)bh * 2048 + qb * 64 + wave * 16) * 64;
    b16x8 qf0 = *(const b16x8*)(Qbase + lc * 64 + quad * 8);
    b16x8 qf1 = *(const b16x8*)(Qbase + lc * 64 + 32 + quad * 8);

    f32x4 oacc[4] = {};
    float lsum = 0.f;

    auto flash_tile = [&](const b16* Kc, const b16* Vc) {
#pragma unroll
        for (int ks = 0; ks < 2; ++ks) {
            b16x8 pf;
#pragma unroll
            for (int t = 0; t < 2; ++t) {
                const int krow = ks * 32 + (lc >> 2) * 8 + t * 4 + (lc & 3);
                b16x8 kf0 = *(const b16x8*)(Kc + krow * 64 + ((0 * 4 + quad) ^ SW(krow)) * 8);
                b16x8 kf1 = *(const b16x8*)(Kc + krow * 64 + ((1 * 4 + quad) ^ SW(krow)) * 8);
                f32x4 s = {};
                __builtin_amdgcn_s_setprio(1);
                s = __builtin_amdgcn_mfma_f32_16x16x32_bf16(kf0, qf0, s, 0, 0, 0);
                s = __builtin_amdgcn_mfma_f32_16x16x32_bf16(kf1, qf1, s, 0, 0, 0);
                __builtin_amdgcn_s_setprio(0);
                // lane holds S[key = ks*32 + quad*8 + t*4 + r][q = lc]
                float e0 = EXP2F(s[0]), e1 = EXP2F(s[1]);
                float e2 = EXP2F(s[2]), e3 = EXP2F(s[3]);
                lsum += (e0 + e1) + (e2 + e3);
                pf[t * 4 + 0] = (b16)e0;
                pf[t * 4 + 1] = (b16)e1;
                pf[t * 4 + 2] = (b16)e2;
                pf[t * 4 + 3] = (b16)e3;
            }
            b16x8 vf[4];
#pragma unroll
            for (int dt = 0; dt < 4; ++dt) {
                const int row = dt * 16 + lc;
                vf[dt] = *(const b16x8*)(Vc + row * 64 + ((ks * 4 + quad) ^ SW(row)) * 8);
            }
            __builtin_amdgcn_s_setprio(1);
#pragma unroll
            for (int dt = 0; dt < 4; ++dt)
                oacc[dt] = __builtin_amdgcn_mfma_f32_16x16x32_bf16(
                    pf, vf[dt], oacc[dt], 0, 0, 0);
            __builtin_amdgcn_s_setprio(0);
        }
    };

    for (int kt = 0; kt < 32; kt += 2) {
        // half 0: stage buf1 (tile kt+1), compute buf0 (tile kt)
        FSTAGE(1);
        asm volatile("s_waitcnt vmcnt(4)" ::: "memory");
        __builtin_amdgcn_s_barrier();
        __builtin_amdgcn_sched_barrier(0);
        flash_tile(Ks, Vs);
        __builtin_amdgcn_sched_barrier(0);
        __builtin_amdgcn_s_barrier();
        // half 1: stage buf0 (tile kt+2) unless done, compute buf1 (tile kt+1)
        if (kt + 2 < 32) {
            FSTAGE(0);
            asm volatile("s_waitcnt vmcnt(4)" ::: "memory");
        } else {
            asm volatile("s_waitcnt vmcnt(0)" ::: "memory");
        }
        __builtin_amdgcn_s_barrier();
        __builtin_amdgcn_sched_barrier(0);
        flash_tile(Ks + 4096, Vs + 4096);
        __builtin_amdgcn_sched_barrier(0);
        __builtin_amdgcn_s_barrier();
    }
#undef FSTAGE

    // reduce l across quads (lane holds partial l for q=lc)
    lsum += __shfl_xor(lsum, 16, 64);
    lsum += __shfl_xor(lsum, 32, 64);

    // redistribute l via per-wave LDS, write AO directly
    if (quad == 0) Lred[wave][lc] = lsum;
    const int b = bh >> 4, h = bh & 15;
#pragma unroll
    for (int r = 0; r < 4; ++r) {
        const float inv = 1.0f / Lred[wave][quad * 4 + r];
        const int s = qb * 64 + wave * 16 + quad * 4 + r;
#pragma unroll
        for (int dt = 0; dt < 4; ++dt)
            AO[(size_t)(b * 2048 + s) * 1024 + h * 64 + dt * 16 + lc] =
                (b16)(oacc[dt][r] * inv);
    }
}

// ---------- kernel 4: output projection, fp32 epilogue ----------
__global__ __launch_bounds__(256, 2) void k_gemm_out(
    const b16* __restrict__ A, const b16* __restrict__ Bt,
    const float* __restrict__ bo, float* __restrict__ out) {
    __shared__ __align__(16) b16 As[2 * 128 * 32];
    __shared__ __align__(16) b16 Bs[2 * 128 * 32];
    const int bm = blockIdx.x, bn = blockIdx.y;
    const int tid = threadIdx.x;
    const int lane = tid & 63, wave = tid >> 6;
    const int wm = wave & 1, wn = wave >> 1;
    const int quad = lane >> 4, lc = lane & 15;

    f32x4 acc[4][4] = {};
    gemm128_core(A + (size_t)(bm * 128) * 1024, Bt + (size_t)(bn * 128) * 1024,
                 As, Bs, tid, acc);

#pragma unroll
    for (int nt = 0; nt < 4; ++nt) {
        const int n = bn * 128 + wn * 64 + nt * 16 + lc;
        const float bval = bo[n];
#pragma unroll
        for (int mt = 0; mt < 4; ++mt) {
            const int m0 = bm * 128 + wm * 64 + mt * 16 + quad * 4;
#pragma unroll
            for (int r = 0; r < 4; ++r)
                out[(size_t)(m0 + r) * 1024 + n] = acc[mt][nt][r] + bval;
        }
    }
}

// ---------- launcher ----------
extern "C" void kernel_launch(void* const* d_in, const int* in_sizes, int n_in,
                              void* d_out, int out_size, void* d_ws, size_t ws_size,
                              hipStream_t stream) {
    const float* x  = (const float*)d_in[0];
    const float* Wq = (const float*)d_in[1];
    const float* bq = (const float*)d_in[2];
    const float* Wk = (const float*)d_in[3];
    const float* bk = (const float*)d_in[4];
    const float* Wv = (const float*)d_in[5];
    const float* bv = (const float*)d_in[6];
    const float* Wo = (const float*)d_in[7];
    const float* bo = (const float*)d_in[8];
    float* out = (float*)d_out;

    char* ws = (char*)d_ws;
    const size_t MB = 1024 * 1024;
    b16* Xb  = (b16*)(ws);             // [4096][1024] bf16 (dead after qkv)
    b16* AO  = (b16*)(ws);             // [4096][1024] bf16 (overlay on Xb)
    b16* WtQ = (b16*)(ws + 8 * MB);    // [3072][1024] bf16
    b16* Wot = (b16*)(ws + 14 * MB);   // [1024][1024] bf16
    b16* Qg  = (b16*)(ws + 16 * MB);   // [32][2048][64] bf16 (pre-scaled)
    b16* Kg  = (b16*)(ws + 24 * MB);   // [32][2048][64] bf16
    b16* Vtg = (b16*)(ws + 32 * MB);   // [32][64][2048] bf16

    k_prep<<<dim3(32, 32, 5), 256, 0, stream>>>(x, Wq, Wk, Wv, Wo, Xb, WtQ, Wot);
    k_gemm_qkv<<<dim3(32, 24), 256, 0, stream>>>(Xb, WtQ, bq, bk, bv, Qg, Kg, Vtg);
    k_flash<<<dim3(1024), 256, 0, stream>>>(Qg, Kg, Vtg, AO);
    k_gemm_out<<<dim3(32, 8), 256, 0, stream>>>(AO, Wot, bo, out);
}